// Round 19
// baseline (179.004 us; speedup 1.0000x reference)
//
#include <hip/hip_runtime.h>
#include <hip/hip_bf16.h>

typedef __attribute__((ext_vector_type(8))) short bf16x8;    // 8 bf16 = 4 VGPR
typedef __attribute__((ext_vector_type(16))) float f32x16;   // 32x32 accumulator
typedef unsigned int u32;

#define MOD_SCALE 0.04419417382415922f     // 1/sqrt(512)
#define CONV_SCALE 0.014731391274719742f   // 1/sqrt(512*9)

__device__ __forceinline__ unsigned short f2bf(float f) {
  union { float f; u32 u; } v; v.f = f;
  u32 r = v.u + 0x7fffu + ((v.u >> 16) & 1u);   // RNE
  return (unsigned short)(r >> 16);
}

__device__ __forceinline__ void gload_lds16(const void* g, void* l) {
  __builtin_amdgcn_global_load_lds(
      (const __attribute__((address_space(1))) u32*)g,
      (__attribute__((address_space(3))) u32*)l, 16, 0, 0);
}

// ---- k_prep: blocks 0..1023 = weight prep (LDS-coalesced), 1024..1039 = style GEMV.
// wb layout: [tap 9][icb 32][oc 512][ic 16] bf16.
__global__ void k_prep(const float* __restrict__ wsrc, ushort* __restrict__ wb,
                       float* __restrict__ wsq, float* __restrict__ zerobuf,
                       const float* __restrict__ style, const float* __restrict__ mw,
                       const float* __restrict__ mb, float* __restrict__ s) {
  __shared__ float wtile[2304];
  const int t = threadIdx.x;
  if (blockIdx.x < 1024) {
    const float4* s4 = (const float4*)(wsrc + (size_t)blockIdx.x * 2304);
    float4* w4 = (float4*)wtile;
    w4[t] = s4[t];
    w4[t + 256] = s4[t + 256];
    if (t < 64) w4[t + 512] = s4[t + 512];
    __syncthreads();
    int idx = blockIdx.x * 256 + t;   // oc*512+ic
    int oc = idx >> 9, ic = idx & 511;
    int icb = ic >> 4, icr = ic & 15;
    if (blockIdx.x == 0 && t < 16) zerobuf[t] = 0.f;
    float sq = 0.f;
    #pragma unroll
    for (int tap = 0; tap < 9; ++tap) {
      float v = wtile[t * 9 + tap];
      sq += v * v;
      wb[((tap * 32 + icb) * 512 + oc) * 16 + icr] = f2bf(v);
    }
    wsq[idx] = sq;
  } else {
    int idx = (blockIdx.x - 1024) * 256 + t;   // b*512+ic
    int b = idx >> 9, ic = idx & 511;
    const float4* wr = (const float4*)(mw + ic * 512);
    const float4* sr = (const float4*)(style + b * 512);
    float acc = 0.f;
    #pragma unroll 4
    for (int k = 0; k < 128; ++k) {
      float4 a = wr[k], c = sr[k];
      acc += a.x * c.x + a.y * c.y + a.z * c.z + a.w * c.w;
    }
    s[idx] = acc * MOD_SCALE + mb[ic];
  }
}

// ---- k_xform: 512 blocks (b, y). All blocks: xsb[b][y][icb 32][x 64][ic 16] =
// bf16(x[b][ic][y][x] * s[b][ic]). Blocks with y<8 additionally compute
// dscale[b][y*64 .. y*64+64] from wsq + s (fold runs concurrently with the other
// 448 blocks — beats both a separate demod dispatch and an appended demod tail).
__global__ void k_xform(const float* __restrict__ x, const float* __restrict__ s,
                        ushort* __restrict__ xsb, const float* __restrict__ wsq,
                        float* __restrict__ dscale) {
  __shared__ float red[256];
  const int t = threadIdx.x;
  const int y = blockIdx.x & 63, b = blockIdx.x >> 6;
  const int px = t & 63, icq = t >> 6;
  #pragma unroll
  for (int i = 0; i < 8; ++i) {
    int icb = i * 4 + icq;
    union { ushort u[16]; uint4 v[2]; } pk;
    #pragma unroll
    for (int j = 0; j < 16; ++j) {
      int ic = icb * 16 + j;
      float v = x[(b * 512 + ic) * 4096 + y * 64 + px] * s[b * 512 + ic];
      pk.u[j] = f2bf(v);
    }
    ushort* dst = xsb + ((size_t)((b * 64 + y) * 32 + icb) * 64 + px) * 16;
    *(uint4*)dst = pk.v[0];
    *(uint4*)(dst + 8) = pk.v[1];
  }
  if (y < 8) {
    // demod for oc in [y*64, y*64+64)
    const int oc_l = t & 63, kq = t >> 6;
    const float4* wq = (const float4*)(wsq + (size_t)(y * 64 + oc_l) * 512) + kq * 32;
    const float4* sp = (const float4*)(s + b * 512) + kq * 32;
    float part = 0.f;
    #pragma unroll 4
    for (int k = 0; k < 32; ++k) {
      float4 a = wq[k], c = sp[k];
      part += a.x * c.x * c.x + a.y * c.y * c.y + a.z * c.z * c.z + a.w * c.w * c.w;
    }
    red[t] = part;
    __syncthreads();
    if (t < 64)
      dscale[b * 512 + y * 64 + t] = CONV_SCALE * rsqrtf(
          CONV_SCALE * CONV_SCALE * (red[t] + red[t + 64] + red[t + 128] + red[t + 192]) + 1e-8f);
  }
}

// ---- k_conv: implicit-GEMM conv, mfma_f32_32x32x16_bf16 (R7/R16 structure, 125 us
// verified x6) + ONE change: s_setprio(1) around each 24-MFMA cluster (T5).
// Rationale: 2 independent blocks/CU provide cross-block wave role diversity;
// priority biases the SIMD scheduler toward MFMA-issuing waves during the other
// block's staging/LDS bursts (continuous arbitration vs R10's one-shot stagger).
#define ABYTES 18432
#define BUFB   39552
#define SMEMSZ (2 * BUFB + 256)
__global__ __launch_bounds__(256, 2) void k_conv(
    const ushort* __restrict__ wb, const ushort* __restrict__ xsb,
    const float* __restrict__ dscale, const float* __restrict__ zerobuf,
    float* __restrict__ out) {
  const int yb = blockIdx.x, ocb = blockIdx.y, b = blockIdx.z;
  const int t = threadIdx.x;
  const int wv = t >> 6, l = t & 63;
  const int lc = l & 31, lh = l >> 5;
  const int wvr = wv >> 1, wvp = wv & 1;
  const int y0 = yb * 8, oc0 = ocb * 64;

  extern __shared__ char smem[];
  float* dss = (float*)(smem + 2 * BUFB);
  if (t < 64) dss[t] = dscale[b * 512 + oc0 + t];

  f32x16 acc[4][2];
  #pragma unroll
  for (int rr = 0; rr < 4; ++rr)
    #pragma unroll
    for (int ocf = 0; ocf < 2; ++ocf)
      #pragma unroll
      for (int k = 0; k < 16; ++k)
        acc[rr][ocf][k] = 0.f;

  // A staging: 1152 chunks (4 full iters + t<128)
  const char* asrc[5];
  #pragma unroll
  for (int i = 0; i < 5; ++i) {
    int cid = i * 256 + t;
    int tap = cid >> 7, cc = cid & 127;
    int oc_l = cc >> 1, h = cc & 1;
    asrc[i] = (const char*)wb + (size_t)tap * 524288 + (size_t)(oc0 + oc_l) * 32 + h * 16;
  }
  // B staging: 1320 chunks = 10 rows x 132 (cols 0,1,130,131 = zero border)
  const char* bsrc[6];
  int bstride[6];
  #pragma unroll
  for (int i = 0; i < 6; ++i) {
    int cid = i * 256 + t;
    int r = cid / 132, rem = cid - r * 132;
    int yy = y0 - 1 + r;
    bool interior = (rem >= 2) && (rem < 130) && ((unsigned)yy < 64u);
    bsrc[i] = interior
        ? (const char*)xsb + (size_t)(b * 64 + yy) * 65536 + (rem - 2) * 16
        : (const char*)zerobuf;
    bstride[i] = interior ? 2048 : 0;
  }

  const int apo = (lc * 2 + lh) * 16;
  const int bco = (wvp * 32 + lc) * 32 + lh * 16;

  auto STAGE = [&](int bo, int icb) {
    char* Ab = smem + bo;
    char* Bb = Ab + ABYTES;
    const int aoff = icb * 16384;
    #pragma unroll
    for (int i = 0; i < 4; ++i)
      gload_lds16(asrc[i] + aoff, Ab + i * 4096 + wv * 1024);
    if (t < 128)
      gload_lds16(asrc[4] + aoff, Ab + 16384 + wv * 1024);
    #pragma unroll
    for (int i = 0; i < 5; ++i)
      gload_lds16(bsrc[i] + icb * bstride[i], Bb + i * 4096 + wv * 1024);
    if (t < 40)
      gload_lds16(bsrc[5] + icb * bstride[5], Bb + 20480);
  };

  auto COMPUTE = [&](int bo) {
    const char* Ab = smem + bo;
    const char* Bb = smem + bo + ABYTES;
    #pragma unroll
    for (int dx = 0; dx < 3; ++dx) {
      bf16x8 bfr[6];
      #pragma unroll
      for (int j = 0; j < 6; ++j)
        bfr[j] = *(const bf16x8*)(Bb + (wvr * 4 + j) * 2112 + dx * 32 + bco);
      bf16x8 af[3][2];
      #pragma unroll
      for (int dy = 0; dy < 3; ++dy)
        #pragma unroll
        for (int ocf = 0; ocf < 2; ++ocf)
          af[dy][ocf] = *(const bf16x8*)(Ab + (dy * 3 + dx) * 2048 + ocf * 1024 + apo);
      __builtin_amdgcn_s_setprio(1);
      #pragma unroll
      for (int dy = 0; dy < 3; ++dy)
        #pragma unroll
        for (int rr = 0; rr < 4; ++rr)
          #pragma unroll
          for (int ocf = 0; ocf < 2; ++ocf)
            acc[rr][ocf] = __builtin_amdgcn_mfma_f32_32x32x16_bf16(
                af[dy][ocf], bfr[rr + dy], acc[rr][ocf], 0, 0, 0);
      __builtin_amdgcn_s_setprio(0);
    }
  };

  STAGE(0, 0);
  __syncthreads();
  #pragma unroll 1
  for (int it = 0; it < 32; it += 2) {
    STAGE(BUFB, it + 1);
    COMPUTE(0);
    __syncthreads();
    if (it < 30) STAGE(0, it + 2);
    COMPUTE(BUFB);
    __syncthreads();
  }

  // ---- epilogue: 32x32 D layout [m74/m101]: col(px)=lane&31, row(oc)=(reg&3)+8*(reg>>2)+4*(lane>>5)
  #pragma unroll
  for (int rr = 0; rr < 4; ++rr) {
    const int y_row = y0 + wvr * 4 + rr;
    #pragma unroll
    for (int ocf = 0; ocf < 2; ++ocf) {
      #pragma unroll
      for (int reg = 0; reg < 16; ++reg) {
        int oc_l = ocf * 32 + (reg & 3) + 8 * (reg >> 2) + 4 * lh;
        out[(size_t)(b * 512 + oc0 + oc_l) * 4096 + y_row * 64 + wvp * 32 + lc]
            = acc[rr][ocf][reg] * dss[oc_l];
      }
    }
  }
}

extern "C" void kernel_launch(void* const* d_in, const int* in_sizes, int n_in,
                              void* d_out, int out_size, void* d_ws, size_t ws_size,
                              hipStream_t stream) {
  const float* x     = (const float*)d_in[0];  // [8,512,64,64]
  const float* style = (const float*)d_in[1];  // [8,512]
  const float* mw    = (const float*)d_in[2];  // [512,512]
  const float* mb    = (const float*)d_in[3];  // [512]
  const float* wsrc  = (const float*)d_in[4];  // [1,512,512,3,3]
  float* out = (float*)d_out;

  char* ws = (char*)d_ws;
  float*  zerobuf = (float*)(ws + 0);          //    64 B
  float*  s       = (float*)(ws + 256);        //  16 KB
  float*  dscale  = (float*)(ws + 16640);      //  16 KB
  float*  wsq     = (float*)(ws + 33024);      //   1 MB
  ushort* wb      = (ushort*)(ws + 1081600);   // 4.5 MB  [9][32][512][16] bf16
  ushort* xsb     = (ushort*)(ws + 5800192);   //  32 MB  [8][64][32][64][16] bf16

  hipFuncSetAttribute(reinterpret_cast<const void*>(k_conv),
                      hipFuncAttributeMaxDynamicSharedMemorySize, SMEMSZ);

  k_prep<<<dim3(1040), dim3(256), 0, stream>>>(wsrc, wb, wsq, zerobuf, style, mw, mb, s);
  k_xform<<<dim3(512), dim3(256), 0, stream>>>(x, s, xsb, wsq, dscale);
  k_conv<<<dim3(8, 8, 8), dim3(256), SMEMSZ, stream>>>(wb, xsb, dscale, zerobuf, out);
}

// Round 20
// 171.827 us; speedup vs baseline: 1.0418x; 1.0418x over previous
//
#include <hip/hip_runtime.h>
#include <hip/hip_bf16.h>

typedef __attribute__((ext_vector_type(8))) short bf16x8;    // 8 bf16 = 4 VGPR
typedef __attribute__((ext_vector_type(16))) float f32x16;   // 32x32 accumulator
typedef unsigned int u32;

#define MOD_SCALE 0.04419417382415922f     // 1/sqrt(512)
#define CONV_SCALE 0.014731391274719742f   // 1/sqrt(512*9)

__device__ __forceinline__ unsigned short f2bf(float f) {
  union { float f; u32 u; } v; v.f = f;
  u32 r = v.u + 0x7fffu + ((v.u >> 16) & 1u);   // RNE
  return (unsigned short)(r >> 16);
}

__device__ __forceinline__ void gload_lds16(const void* g, void* l) {
  __builtin_amdgcn_global_load_lds(
      (const __attribute__((address_space(1))) u32*)g,
      (__attribute__((address_space(3))) u32*)l, 16, 0, 0);
}

// ---- k_prep: blocks 0..1023 = weight prep (LDS-coalesced), 1024..1039 = style GEMV.
// wb layout: [tap 9][icb 32][oc 512][ic 16] bf16.
__global__ void k_prep(const float* __restrict__ wsrc, ushort* __restrict__ wb,
                       float* __restrict__ wsq, float* __restrict__ zerobuf,
                       const float* __restrict__ style, const float* __restrict__ mw,
                       const float* __restrict__ mb, float* __restrict__ s) {
  __shared__ float wtile[2304];
  const int t = threadIdx.x;
  if (blockIdx.x < 1024) {
    const float4* s4 = (const float4*)(wsrc + (size_t)blockIdx.x * 2304);
    float4* w4 = (float4*)wtile;
    w4[t] = s4[t];
    w4[t + 256] = s4[t + 256];
    if (t < 64) w4[t + 512] = s4[t + 512];
    __syncthreads();
    int idx = blockIdx.x * 256 + t;   // oc*512+ic
    int oc = idx >> 9, ic = idx & 511;
    int icb = ic >> 4, icr = ic & 15;
    if (blockIdx.x == 0 && t < 16) zerobuf[t] = 0.f;
    float sq = 0.f;
    #pragma unroll
    for (int tap = 0; tap < 9; ++tap) {
      float v = wtile[t * 9 + tap];
      sq += v * v;
      wb[((tap * 32 + icb) * 512 + oc) * 16 + icr] = f2bf(v);
    }
    wsq[idx] = sq;
  } else {
    int idx = (blockIdx.x - 1024) * 256 + t;   // b*512+ic
    int b = idx >> 9, ic = idx & 511;
    const float4* wr = (const float4*)(mw + ic * 512);
    const float4* sr = (const float4*)(style + b * 512);
    float acc = 0.f;
    #pragma unroll 4
    for (int k = 0; k < 128; ++k) {
      float4 a = wr[k], c = sr[k];
      acc += a.x * c.x + a.y * c.y + a.z * c.z + a.w * c.w;
    }
    s[idx] = acc * MOD_SCALE + mb[ic];
  }
}

// ---- k_xform: 512 blocks (b, y). All blocks: xsb[b][y][icb 32][x 64][ic 16] =
// bf16(x[b][ic][y][x] * s[b][ic]). Blocks with y<8 additionally compute
// dscale[b][y*64 .. y*64+64] from wsq + s (fold runs concurrently with the other
// 448 blocks — beats both a separate demod dispatch and an appended demod tail).
__global__ void k_xform(const float* __restrict__ x, const float* __restrict__ s,
                        ushort* __restrict__ xsb, const float* __restrict__ wsq,
                        float* __restrict__ dscale) {
  __shared__ float red[256];
  const int t = threadIdx.x;
  const int y = blockIdx.x & 63, b = blockIdx.x >> 6;
  const int px = t & 63, icq = t >> 6;
  #pragma unroll
  for (int i = 0; i < 8; ++i) {
    int icb = i * 4 + icq;
    union { ushort u[16]; uint4 v[2]; } pk;
    #pragma unroll
    for (int j = 0; j < 16; ++j) {
      int ic = icb * 16 + j;
      float v = x[(b * 512 + ic) * 4096 + y * 64 + px] * s[b * 512 + ic];
      pk.u[j] = f2bf(v);
    }
    ushort* dst = xsb + ((size_t)((b * 64 + y) * 32 + icb) * 64 + px) * 16;
    *(uint4*)dst = pk.v[0];
    *(uint4*)(dst + 8) = pk.v[1];
  }
  if (y < 8) {
    // demod for oc in [y*64, y*64+64)
    const int oc_l = t & 63, kq = t >> 6;
    const float4* wq = (const float4*)(wsq + (size_t)(y * 64 + oc_l) * 512) + kq * 32;
    const float4* sp = (const float4*)(s + b * 512) + kq * 32;
    float part = 0.f;
    #pragma unroll 4
    for (int k = 0; k < 32; ++k) {
      float4 a = wq[k], c = sp[k];
      part += a.x * c.x * c.x + a.y * c.y * c.y + a.z * c.z * c.z + a.w * c.w * c.w;
    }
    red[t] = part;
    __syncthreads();
    if (t < 64)
      dscale[b * 512 + y * 64 + t] = CONV_SCALE * rsqrtf(
          CONV_SCALE * CONV_SCALE * (red[t] + red[t + 64] + red[t + 128] + red[t + 192]) + 1e-8f);
  }
}

// ---- k_conv: implicit-GEMM conv, mfma_f32_32x32x16_bf16 (exact R7/R16 structure —
// session best: 125 us, MfmaUtil ~60%, reproduced x6; every scheduling deviation
// regressed: counted-vmcnt x2, asm ds_read pipeline, sleep stagger, K-rotation,
// setprio). Block 64oc x 8rows x 64px, 4 waves; wave = 4rows x 32px x 64oc,
// acc[4][2] f32x16. BK=16, A+B LDS double-buffered; STAGE(t+1) issued before
// COMPUTE(t); one __syncthreads per K-step.
#define ABYTES 18432
#define BUFB   39552
#define SMEMSZ (2 * BUFB + 256)
__global__ __launch_bounds__(256, 2) void k_conv(
    const ushort* __restrict__ wb, const ushort* __restrict__ xsb,
    const float* __restrict__ dscale, const float* __restrict__ zerobuf,
    float* __restrict__ out) {
  const int yb = blockIdx.x, ocb = blockIdx.y, b = blockIdx.z;
  const int t = threadIdx.x;
  const int wv = t >> 6, l = t & 63;
  const int lc = l & 31, lh = l >> 5;
  const int wvr = wv >> 1, wvp = wv & 1;
  const int y0 = yb * 8, oc0 = ocb * 64;

  extern __shared__ char smem[];
  float* dss = (float*)(smem + 2 * BUFB);
  if (t < 64) dss[t] = dscale[b * 512 + oc0 + t];

  f32x16 acc[4][2];
  #pragma unroll
  for (int rr = 0; rr < 4; ++rr)
    #pragma unroll
    for (int ocf = 0; ocf < 2; ++ocf)
      #pragma unroll
      for (int k = 0; k < 16; ++k)
        acc[rr][ocf][k] = 0.f;

  // A staging: 1152 chunks (4 full iters + t<128)
  const char* asrc[5];
  #pragma unroll
  for (int i = 0; i < 5; ++i) {
    int cid = i * 256 + t;
    int tap = cid >> 7, cc = cid & 127;
    int oc_l = cc >> 1, h = cc & 1;
    asrc[i] = (const char*)wb + (size_t)tap * 524288 + (size_t)(oc0 + oc_l) * 32 + h * 16;
  }
  // B staging: 1320 chunks = 10 rows x 132 (cols 0,1,130,131 = zero border)
  const char* bsrc[6];
  int bstride[6];
  #pragma unroll
  for (int i = 0; i < 6; ++i) {
    int cid = i * 256 + t;
    int r = cid / 132, rem = cid - r * 132;
    int yy = y0 - 1 + r;
    bool interior = (rem >= 2) && (rem < 130) && ((unsigned)yy < 64u);
    bsrc[i] = interior
        ? (const char*)xsb + (size_t)(b * 64 + yy) * 65536 + (rem - 2) * 16
        : (const char*)zerobuf;
    bstride[i] = interior ? 2048 : 0;
  }

  const int apo = (lc * 2 + lh) * 16;
  const int bco = (wvp * 32 + lc) * 32 + lh * 16;

  auto STAGE = [&](int bo, int icb) {
    char* Ab = smem + bo;
    char* Bb = Ab + ABYTES;
    const int aoff = icb * 16384;
    #pragma unroll
    for (int i = 0; i < 4; ++i)
      gload_lds16(asrc[i] + aoff, Ab + i * 4096 + wv * 1024);
    if (t < 128)
      gload_lds16(asrc[4] + aoff, Ab + 16384 + wv * 1024);
    #pragma unroll
    for (int i = 0; i < 5; ++i)
      gload_lds16(bsrc[i] + icb * bstride[i], Bb + i * 4096 + wv * 1024);
    if (t < 40)
      gload_lds16(bsrc[5] + icb * bstride[5], Bb + 20480);
  };

  auto COMPUTE = [&](int bo) {
    const char* Ab = smem + bo;
    const char* Bb = smem + bo + ABYTES;
    #pragma unroll
    for (int dx = 0; dx < 3; ++dx) {
      bf16x8 bfr[6];
      #pragma unroll
      for (int j = 0; j < 6; ++j)
        bfr[j] = *(const bf16x8*)(Bb + (wvr * 4 + j) * 2112 + dx * 32 + bco);
      bf16x8 af[3][2];
      #pragma unroll
      for (int dy = 0; dy < 3; ++dy)
        #pragma unroll
        for (int ocf = 0; ocf < 2; ++ocf)
          af[dy][ocf] = *(const bf16x8*)(Ab + (dy * 3 + dx) * 2048 + ocf * 1024 + apo);
      #pragma unroll
      for (int dy = 0; dy < 3; ++dy)
        #pragma unroll
        for (int rr = 0; rr < 4; ++rr)
          #pragma unroll
          for (int ocf = 0; ocf < 2; ++ocf)
            acc[rr][ocf] = __builtin_amdgcn_mfma_f32_32x32x16_bf16(
                af[dy][ocf], bfr[rr + dy], acc[rr][ocf], 0, 0, 0);
    }
  };

  STAGE(0, 0);
  __syncthreads();
  #pragma unroll 1
  for (int it = 0; it < 32; it += 2) {
    STAGE(BUFB, it + 1);
    COMPUTE(0);
    __syncthreads();
    if (it < 30) STAGE(0, it + 2);
    COMPUTE(BUFB);
    __syncthreads();
  }

  // ---- epilogue: 32x32 D layout [m74/m101]: col(px)=lane&31, row(oc)=(reg&3)+8*(reg>>2)+4*(lane>>5)
  #pragma unroll
  for (int rr = 0; rr < 4; ++rr) {
    const int y_row = y0 + wvr * 4 + rr;
    #pragma unroll
    for (int ocf = 0; ocf < 2; ++ocf) {
      #pragma unroll
      for (int reg = 0; reg < 16; ++reg) {
        int oc_l = ocf * 32 + (reg & 3) + 8 * (reg >> 2) + 4 * lh;
        out[(size_t)(b * 512 + oc0 + oc_l) * 4096 + y_row * 64 + wvp * 32 + lc]
            = acc[rr][ocf][reg] * dss[oc_l];
      }
    }
  }
}

extern "C" void kernel_launch(void* const* d_in, const int* in_sizes, int n_in,
                              void* d_out, int out_size, void* d_ws, size_t ws_size,
                              hipStream_t stream) {
  const float* x     = (const float*)d_in[0];  // [8,512,64,64]
  const float* style = (const float*)d_in[1];  // [8,512]
  const float* mw    = (const float*)d_in[2];  // [512,512]
  const float* mb    = (const float*)d_in[3];  // [512]
  const float* wsrc  = (const float*)d_in[4];  // [1,512,512,3,3]
  float* out = (float*)d_out;

  char* ws = (char*)d_ws;
  float*  zerobuf = (float*)(ws + 0);          //    64 B
  float*  s       = (float*)(ws + 256);        //  16 KB
  float*  dscale  = (float*)(ws + 16640);      //  16 KB
  float*  wsq     = (float*)(ws + 33024);      //   1 MB
  ushort* wb      = (ushort*)(ws + 1081600);   // 4.5 MB  [9][32][512][16] bf16
  ushort* xsb     = (ushort*)(ws + 5800192);   //  32 MB  [8][64][32][64][16] bf16

  hipFuncSetAttribute(reinterpret_cast<const void*>(k_conv),
                      hipFuncAttributeMaxDynamicSharedMemorySize, SMEMSZ);

  k_prep<<<dim3(1040), dim3(256), 0, stream>>>(wsrc, wb, wsq, zerobuf, style, mw, mb, s);
  k_xform<<<dim3(512), dim3(256), 0, stream>>>(x, s, xsb, wsq, dscale);
  k_conv<<<dim3(8, 8, 8), dim3(256), SMEMSZ, stream>>>(wb, xsb, dscale, zerobuf, out);
}